// Round 9
// baseline (576.141 us; speedup 1.0000x reference)
//
#include <hip/hip_runtime.h>

#define N_NODES 100000
#define DIM 64
#define N_TILES (N_NODES / 16)   // 6250 row-tiles of 16

#define BSHIFT 7
#define BN 128                         // nodes per bucket
#define NB ((N_NODES + BN - 1) / BN)   // 782 buckets
#define BC 2048                        // bucket capacity (avg 1600, >11 sigma)
#define CHUNK 8192                     // edges per partition block
#define ACC_STRIDE 65                  // LDS pad: 65 % 32 = 1 decorrelates banks

using bf16x8 = __attribute__((ext_vector_type(8))) short;
using f32x4  = __attribute__((ext_vector_type(4))) float;

// ---- f32 -> bf16 (round-to-nearest-even) -------------------------------

__device__ __forceinline__ unsigned short f2bf(float f) {
    unsigned u = __float_as_uint(f);
    unsigned r = u + 0x7FFFu + ((u >> 16) & 1u);
    return (unsigned short)(r >> 16);
}

// ---- pass 1: partition edges into dst-range buckets --------------------
// Block stages CHUNK edges in LDS, LDS-histograms buckets, claims one
// global range per (bucket,block) with a single atomicAdd, then writes
// packed entries in ~10-entry runs (near line-dense appends).
__global__ void partition_kernel(const int* __restrict__ edge_src,
                                 const int* __restrict__ edge_dst,
                                 int* __restrict__ gcur,
                                 unsigned* __restrict__ buckets, int E) {
    __shared__ unsigned vals[CHUNK];          // 32 KB packed entries
    __shared__ unsigned short bkt[CHUNK];     // 16 KB bucket ids
    __shared__ int hist[NB];                  // 3.1 KB
    __shared__ int gb[NB];
    __shared__ int loff[NB];
    const int tid = threadIdx.x;

    for (int i = tid; i < NB; i += blockDim.x) hist[i] = 0;
    __syncthreads();

    const int e0 = blockIdx.x * CHUNK;
    int e1 = e0 + CHUNK; if (e1 > E) e1 = E;
    const int m = e1 - e0;

    for (int i = tid; i < m; i += blockDim.x) {
        int d = edge_dst[e0 + i];
        int s = edge_src[e0 + i];
        int b = d >> BSHIFT;
        vals[i] = ((unsigned)(d & (BN - 1)) << 20) | (unsigned)s;
        bkt[i] = (unsigned short)b;
        atomicAdd(&hist[b], 1);
    }
    __syncthreads();

    for (int b = tid; b < NB; b += blockDim.x) {
        int c = hist[b];
        loff[b] = 0;
        if (c > 0) gb[b] = atomicAdd(&gcur[b], c);
    }
    __syncthreads();

    for (int i = tid; i < m; i += blockDim.x) {
        int b = bkt[i];
        int pos = gb[b] + atomicAdd(&loff[b], 1);
        if (pos < BC) buckets[(size_t)b * BC + pos] = vals[i];
    }
}

// ---- transform: y = x @ W  (f32 in, bf16 out) via MFMA ------------------
__global__ void transform_kernel(const float* __restrict__ x,
                                 const float* __restrict__ W,
                                 ushort* __restrict__ y) {
    __shared__ ushort lds[4 * 16 * 72];   // per wave: 16 rows x 72 (144B pad)
    const int tid  = threadIdx.x;
    const int lane = tid & 63;
    const int w    = tid >> 6;
    const int l15  = lane & 15;
    const int l4   = lane >> 4;           // 0..3

    // B fragments: bfrag[ct][kt][j] = bf16(W[kt*32 + l4*8 + j][ct*16 + l15])
    bf16x8 bfrag[4][2];
#pragma unroll
    for (int ct = 0; ct < 4; ++ct)
#pragma unroll
        for (int kt = 0; kt < 2; ++kt)
#pragma unroll
            for (int j = 0; j < 8; ++j) {
                int k = kt * 32 + l4 * 8 + j;
                int c = ct * 16 + l15;
                bfrag[ct][kt][j] = (short)f2bf(W[k * DIM + c]);
            }

    ushort* myl = lds + w * (16 * 72);
    const int gw = blockIdx.x * 4 + w;
    const int nw = gridDim.x * 4;

    for (int rt = gw; rt < N_TILES; rt += nw) {
        const float* xt = x + (size_t)rt * 16 * DIM;

        f32x4 zero = {0.f, 0.f, 0.f, 0.f};
        f32x4 acc0 = zero, acc1 = zero, acc2 = zero, acc3 = zero;
#pragma unroll
        for (int kt = 0; kt < 2; ++kt) {
            const float* ap = xt + (size_t)l15 * DIM + kt * 32 + l4 * 8;
            float4 p0 = *(const float4*)(ap);
            float4 p1 = *(const float4*)(ap + 4);
            bf16x8 afrag;
            afrag[0] = (short)f2bf(p0.x); afrag[1] = (short)f2bf(p0.y);
            afrag[2] = (short)f2bf(p0.z); afrag[3] = (short)f2bf(p0.w);
            afrag[4] = (short)f2bf(p1.x); afrag[5] = (short)f2bf(p1.y);
            afrag[6] = (short)f2bf(p1.z); afrag[7] = (short)f2bf(p1.w);
            acc0 = __builtin_amdgcn_mfma_f32_16x16x32_bf16(afrag, bfrag[0][kt], acc0, 0, 0, 0);
            acc1 = __builtin_amdgcn_mfma_f32_16x16x32_bf16(afrag, bfrag[1][kt], acc1, 0, 0, 0);
            acc2 = __builtin_amdgcn_mfma_f32_16x16x32_bf16(afrag, bfrag[2][kt], acc2, 0, 0, 0);
            acc3 = __builtin_amdgcn_mfma_f32_16x16x32_bf16(afrag, bfrag[3][kt], acc3, 0, 0, 0);
        }

        // D layout: col = lane&15 (+ct*16), row = (lane>>4)*4 + reg.
#pragma unroll
        for (int r = 0; r < 4; ++r) {
            int m = l4 * 4 + r;
            myl[m * 72 +  0 + l15] = f2bf(acc0[r]);
            myl[m * 72 + 16 + l15] = f2bf(acc1[r]);
            myl[m * 72 + 32 + l15] = f2bf(acc2[r]);
            myl[m * 72 + 48 + l15] = f2bf(acc3[r]);
        }
        // Read back 32B per lane, store y coalesced.
        int rr = lane >> 2, q = lane & 3;
        const uint4* src = (const uint4*)(myl + rr * 72 + q * 16);
        uint4 d0 = src[0];
        uint4 d1 = src[1];
        ushort* dst = y + ((size_t)(rt * 16 + rr)) * DIM + q * 16;
        *(uint4*)(dst)     = d0;
        *(uint4*)(dst + 8) = d1;
    }
}

// ---- pass 2: per-bucket scatter-accumulate in LDS + dense out ----------
// One block per bucket. Wave handles 4 edges (16 lanes x uint2 of y row),
// converts bf16->f32, ds_add_f32 into acc[dl][.]; then out = acc + bias
// written fully coalesced (float4).
__global__ void scatter_accum_kernel(const ushort* __restrict__ y,
                                     const int* __restrict__ gcur,
                                     const unsigned* __restrict__ buckets,
                                     const float* __restrict__ bias,
                                     float* __restrict__ out) {
    __shared__ float acc[BN * ACC_STRIDE];   // 33.3 KB
    const int tid  = threadIdx.x;
    const int lane = tid & 63;
    const int w    = tid >> 6;    // 0..3
    const int g    = lane >> 4;   // edge in quad
    const int f    = lane & 15;
    const int b    = blockIdx.x;

    for (int i = tid; i < BN * ACC_STRIDE; i += blockDim.x) acc[i] = 0.f;
    __syncthreads();

    int cnt = gcur[b];
    if (cnt > BC) cnt = BC;
    const unsigned* __restrict__ bk = buckets + (size_t)b * BC;
    const uint2* __restrict__ y2 = (const uint2*)y;   // row = 16 uint2

    for (int base = w * 4; base < cnt; base += 16) {
        int e = base + g;
        int s, dl;
        if (e < cnt) {
            unsigned v = bk[e];
            s = (int)(v & 0xFFFFFu);
            dl = (int)(v >> 20);
        } else {
            s = N_NODES;   // zero row
            dl = 0;
        }
        uint2 r = y2[(size_t)s * 16 + f];
        float v0 = __uint_as_float(r.x << 16);
        float v1 = __uint_as_float(r.x & 0xffff0000u);
        float v2 = __uint_as_float(r.y << 16);
        float v3 = __uint_as_float(r.y & 0xffff0000u);
        float* a = acc + dl * ACC_STRIDE + f * 4;
        atomicAdd(a + 0, v0);
        atomicAdd(a + 1, v1);
        atomicAdd(a + 2, v2);
        atomicAdd(a + 3, v3);
    }
    __syncthreads();

    const int node0 = b * BN;
    for (int i = tid; i < BN * 16; i += blockDim.x) {
        int r = i >> 4, q = i & 15;
        int nd = node0 + r;
        if (nd >= N_NODES) break;
        const float* a = acc + r * ACC_STRIDE + q * 4;
        float4 bb = ((const float4*)bias)[q];
        float4 o;
        o.x = a[0] + bb.x; o.y = a[1] + bb.y;
        o.z = a[2] + bb.z; o.w = a[3] + bb.w;
        *(float4*)(out + (size_t)nd * DIM + q * 4) = o;
    }
}

// ---- Launch ------------------------------------------------------------

extern "C" void kernel_launch(void* const* d_in, const int* in_sizes, int n_in,
                              void* d_out, int out_size, void* d_ws, size_t ws_size,
                              hipStream_t stream) {
    const float* x        = (const float*)d_in[0];
    const int*   edge_src = (const int*)d_in[1];
    const int*   edge_dst = (const int*)d_in[2];
    const float* W        = (const float*)d_in[3];
    const float* b        = (const float*)d_in[4];
    float* out = (float*)d_out;

    const int E = in_sizes[1];

    // ws layout: y[(N+1)*64] bf16 (12.8 MB) | gcur[NB] | buckets[NB*BC] (6.4 MB)
    ushort*   y       = (ushort*)d_ws;
    int*      gcur    = (int*)(y + (size_t)(N_NODES + 1) * DIM);
    unsigned* buckets = (unsigned*)(gcur + NB);

    // zero row at index N_NODES (tail-lane predication target)
    hipMemsetAsync(y + (size_t)N_NODES * DIM, 0, DIM * sizeof(ushort), stream);
    hipMemsetAsync(gcur, 0, NB * sizeof(int), stream);

    {
        const int grid = (E + CHUNK - 1) / CHUNK;   // 153
        partition_kernel<<<grid, 256, 0, stream>>>(edge_src, edge_dst,
                                                   gcur, buckets, E);
    }
    transform_kernel<<<512, 256, 0, stream>>>(x, W, y);
    scatter_accum_kernel<<<NB, 256, 0, stream>>>(y, gcur, buckets, b, out);
}

// Round 10
// 76.339 us; speedup vs baseline: 7.5471x; 7.5471x over previous
//
#include <hip/hip_runtime.h>

#define N_NODES 100000
#define DIM 64
#define N_TILES (N_NODES / 16)   // 6250 row-tiles of 16

#define BSHIFT 7
#define BN 128                         // nodes per bucket
#define NB ((N_NODES + BN - 1) / BN)   // 782 buckets
#define BC 2048                        // bucket capacity (avg 1600, >11 sigma)
#define CHUNK 8192                     // edges per partition block

using bf16x8 = __attribute__((ext_vector_type(8))) short;
using f32x4  = __attribute__((ext_vector_type(4))) float;

// ---- f32 -> bf16 (round-to-nearest-even) -------------------------------

__device__ __forceinline__ unsigned short f2bf(float f) {
    unsigned u = __float_as_uint(f);
    unsigned r = u + 0x7FFFu + ((u >> 16) & 1u);
    return (unsigned short)(r >> 16);
}

// ---- pass 1: partition edges into dst-range buckets --------------------
__global__ void partition_kernel(const int* __restrict__ edge_src,
                                 const int* __restrict__ edge_dst,
                                 int* __restrict__ gcur,
                                 unsigned* __restrict__ buckets, int E) {
    __shared__ unsigned vals[CHUNK];          // 32 KB packed entries
    __shared__ unsigned short bkt[CHUNK];     // 16 KB bucket ids
    __shared__ int hist[NB];
    __shared__ int gb[NB];
    __shared__ int loff[NB];
    const int tid = threadIdx.x;

    for (int i = tid; i < NB; i += blockDim.x) hist[i] = 0;
    __syncthreads();

    const int e0 = blockIdx.x * CHUNK;
    int e1 = e0 + CHUNK; if (e1 > E) e1 = E;
    const int m = e1 - e0;

    for (int i = tid; i < m; i += blockDim.x) {
        int d = edge_dst[e0 + i];
        int s = edge_src[e0 + i];
        int b = d >> BSHIFT;
        vals[i] = ((unsigned)(d & (BN - 1)) << 20) | (unsigned)s;
        bkt[i] = (unsigned short)b;
        atomicAdd(&hist[b], 1);
    }
    __syncthreads();

    for (int b = tid; b < NB; b += blockDim.x) {
        int c = hist[b];
        loff[b] = 0;
        if (c > 0) gb[b] = atomicAdd(&gcur[b], c);
    }
    __syncthreads();

    for (int i = tid; i < m; i += blockDim.x) {
        int b = bkt[i];
        int pos = gb[b] + atomicAdd(&loff[b], 1);
        if (pos < BC) buckets[(size_t)b * BC + pos] = vals[i];
    }
}

// ---- transform: y = x @ W  (f32 in, bf16 out) via MFMA ------------------
__global__ void transform_kernel(const float* __restrict__ x,
                                 const float* __restrict__ W,
                                 ushort* __restrict__ y) {
    __shared__ ushort lds[4 * 16 * 72];
    const int tid  = threadIdx.x;
    const int lane = tid & 63;
    const int w    = tid >> 6;
    const int l15  = lane & 15;
    const int l4   = lane >> 4;

    bf16x8 bfrag[4][2];
#pragma unroll
    for (int ct = 0; ct < 4; ++ct)
#pragma unroll
        for (int kt = 0; kt < 2; ++kt)
#pragma unroll
            for (int j = 0; j < 8; ++j) {
                int k = kt * 32 + l4 * 8 + j;
                int c = ct * 16 + l15;
                bfrag[ct][kt][j] = (short)f2bf(W[k * DIM + c]);
            }

    ushort* myl = lds + w * (16 * 72);
    const int gw = blockIdx.x * 4 + w;
    const int nw = gridDim.x * 4;

    for (int rt = gw; rt < N_TILES; rt += nw) {
        const float* xt = x + (size_t)rt * 16 * DIM;

        f32x4 zero = {0.f, 0.f, 0.f, 0.f};
        f32x4 acc0 = zero, acc1 = zero, acc2 = zero, acc3 = zero;
#pragma unroll
        for (int kt = 0; kt < 2; ++kt) {
            const float* ap = xt + (size_t)l15 * DIM + kt * 32 + l4 * 8;
            float4 p0 = *(const float4*)(ap);
            float4 p1 = *(const float4*)(ap + 4);
            bf16x8 afrag;
            afrag[0] = (short)f2bf(p0.x); afrag[1] = (short)f2bf(p0.y);
            afrag[2] = (short)f2bf(p0.z); afrag[3] = (short)f2bf(p0.w);
            afrag[4] = (short)f2bf(p1.x); afrag[5] = (short)f2bf(p1.y);
            afrag[6] = (short)f2bf(p1.z); afrag[7] = (short)f2bf(p1.w);
            acc0 = __builtin_amdgcn_mfma_f32_16x16x32_bf16(afrag, bfrag[0][kt], acc0, 0, 0, 0);
            acc1 = __builtin_amdgcn_mfma_f32_16x16x32_bf16(afrag, bfrag[1][kt], acc1, 0, 0, 0);
            acc2 = __builtin_amdgcn_mfma_f32_16x16x32_bf16(afrag, bfrag[2][kt], acc2, 0, 0, 0);
            acc3 = __builtin_amdgcn_mfma_f32_16x16x32_bf16(afrag, bfrag[3][kt], acc3, 0, 0, 0);
        }

#pragma unroll
        for (int r = 0; r < 4; ++r) {
            int m = l4 * 4 + r;
            myl[m * 72 +  0 + l15] = f2bf(acc0[r]);
            myl[m * 72 + 16 + l15] = f2bf(acc1[r]);
            myl[m * 72 + 32 + l15] = f2bf(acc2[r]);
            myl[m * 72 + 48 + l15] = f2bf(acc3[r]);
        }
        int rr = lane >> 2, q = lane & 3;
        const uint4* src = (const uint4*)(myl + rr * 72 + q * 16);
        uint4 d0 = src[0];
        uint4 d1 = src[1];
        ushort* dst = y + ((size_t)(rt * 16 + rr)) * DIM + q * 16;
        *(uint4*)(dst)     = d0;
        *(uint4*)(dst + 8) = d1;
    }
}

// ---- pass 2: per-bucket counting sort + register-accumulated gather ----
// One block per bucket. LDS counting sort of the ~1600 entries by local
// node id (cheap index-only DS ops), then each 16-lane group owns one
// node at a time: 4 y-row loads (uint2/lane) in flight, accumulate in
// registers, fused bias, coalesced float4 store. No DS ops on features.
__global__ void sort_gather_kernel(const ushort* __restrict__ y,
                                   const int* __restrict__ gcur,
                                   const unsigned* __restrict__ buckets,
                                   const float* __restrict__ bias,
                                   float* __restrict__ out) {
    __shared__ unsigned vals[BC];      // 8 KB staged entries
    __shared__ unsigned short srt[BC]; // 4 KB sorted src (bucket-local 20b? no: srcs are 20b)
    __shared__ unsigned sorted[BC];    // 8 KB sorted src indices
    __shared__ int h[BN];
    __shared__ int tmp[BN];
    __shared__ int offs[BN + 1];
    __shared__ int cur[BN];
    (void)srt;

    const int tid = threadIdx.x;
    const int b = blockIdx.x;

    int cnt = gcur[b];
    if (cnt > BC) cnt = BC;

    for (int i = tid; i < BN; i += blockDim.x) h[i] = 0;
    __syncthreads();

    const unsigned* __restrict__ bk = buckets + (size_t)b * BC;
    for (int i = tid; i < cnt; i += blockDim.x) {
        unsigned v = bk[i];
        vals[i] = v;
        atomicAdd(&h[v >> 20], 1);
    }
    __syncthreads();

    if (tid < BN) tmp[tid] = h[tid];
    __syncthreads();
    for (int o = 1; o < BN; o <<= 1) {
        int t = 0;
        if (tid < BN && tid >= o) t = tmp[tid - o];
        __syncthreads();
        if (tid < BN) tmp[tid] += t;
        __syncthreads();
    }
    if (tid < BN) {
        int e = tmp[tid] - h[tid];       // exclusive
        offs[tid] = e;
        cur[tid] = e;
    }
    if (tid == 0) offs[BN] = cnt;
    __syncthreads();

    for (int i = tid; i < cnt; i += blockDim.x) {
        unsigned v = vals[i];
        int dl = v >> 20;
        int pos = atomicAdd(&cur[dl], 1);
        sorted[pos] = v & 0xFFFFFu;
    }
    __syncthreads();

    const int grp = tid >> 4;        // 16 groups of 16 lanes
    const int f = tid & 15;
    const uint2* __restrict__ y2 = (const uint2*)y;
    const int node0 = b * BN;
    float4 bb = ((const float4*)bias)[f];

    for (int r = grp; r < BN; r += 16) {
        int nd = node0 + r;
        if (nd >= N_NODES) break;
        int s0i = offs[r], e0i = offs[r + 1];
        float a0 = 0.f, a1 = 0.f, a2 = 0.f, a3 = 0.f;
        for (int i = s0i; i < e0i; i += 4) {
            int i0 = (i + 0 < e0i) ? (int)sorted[i + 0] : N_NODES;
            int i1 = (i + 1 < e0i) ? (int)sorted[i + 1] : N_NODES;
            int i2 = (i + 2 < e0i) ? (int)sorted[i + 2] : N_NODES;
            int i3 = (i + 3 < e0i) ? (int)sorted[i + 3] : N_NODES;
            uint2 v0 = y2[(size_t)i0 * 16 + f];
            uint2 v1 = y2[(size_t)i1 * 16 + f];
            uint2 v2 = y2[(size_t)i2 * 16 + f];
            uint2 v3 = y2[(size_t)i3 * 16 + f];
            a0 += __uint_as_float(v0.x << 16) + __uint_as_float(v1.x << 16)
                + __uint_as_float(v2.x << 16) + __uint_as_float(v3.x << 16);
            a1 += __uint_as_float(v0.x & 0xffff0000u) + __uint_as_float(v1.x & 0xffff0000u)
                + __uint_as_float(v2.x & 0xffff0000u) + __uint_as_float(v3.x & 0xffff0000u);
            a2 += __uint_as_float(v0.y << 16) + __uint_as_float(v1.y << 16)
                + __uint_as_float(v2.y << 16) + __uint_as_float(v3.y << 16);
            a3 += __uint_as_float(v0.y & 0xffff0000u) + __uint_as_float(v1.y & 0xffff0000u)
                + __uint_as_float(v2.y & 0xffff0000u) + __uint_as_float(v3.y & 0xffff0000u);
        }
        float4 o;
        o.x = a0 + bb.x; o.y = a1 + bb.y; o.z = a2 + bb.z; o.w = a3 + bb.w;
        *(float4*)(out + (size_t)nd * DIM + f * 4) = o;
    }
}

// ---- Launch ------------------------------------------------------------

extern "C" void kernel_launch(void* const* d_in, const int* in_sizes, int n_in,
                              void* d_out, int out_size, void* d_ws, size_t ws_size,
                              hipStream_t stream) {
    const float* x        = (const float*)d_in[0];
    const int*   edge_src = (const int*)d_in[1];
    const int*   edge_dst = (const int*)d_in[2];
    const float* W        = (const float*)d_in[3];
    const float* b        = (const float*)d_in[4];
    float* out = (float*)d_out;

    const int E = in_sizes[1];

    // ws layout: y[(N+1)*64] bf16 (12.8 MB) | gcur[NB] | buckets[NB*BC] (6.4 MB)
    ushort*   y       = (ushort*)d_ws;
    int*      gcur    = (int*)(y + (size_t)(N_NODES + 1) * DIM);
    unsigned* buckets = (unsigned*)(gcur + NB);

    // zero row at index N_NODES (tail-lane predication target)
    hipMemsetAsync(y + (size_t)N_NODES * DIM, 0, DIM * sizeof(ushort), stream);
    hipMemsetAsync(gcur, 0, NB * sizeof(int), stream);

    {
        const int grid = (E + CHUNK - 1) / CHUNK;   // 153
        partition_kernel<<<grid, 256, 0, stream>>>(edge_src, edge_dst,
                                                   gcur, buckets, E);
    }
    transform_kernel<<<512, 256, 0, stream>>>(x, W, y);
    sort_gather_kernel<<<NB, 256, 0, stream>>>(y, gcur, buckets, b, out);
}